// Round 6
// baseline (994.096 us; speedup 1.0000x reference)
//
#include <hip/hip_runtime.h>
#include <cstdint>

#pragma clang fp contract(off)

#define N_PTS 8192
#define B_SZ  4
#define K_NN  20
#define O_CH  64
#define QW    64              // queries per block (= lanes per wave)
#define NSW   7               // scanning waves (1..7); wave 0 = drain wave
#define SUBL  1170            // subset length per scan wave (wave 7 gets 1172)
#define WARM  96              // warm-up candidates per scan thread (values-only)
#define CAP   8               // real slots per thread per chunk (SPAD has +1 spare)
#define SPAD  9               // stack row stride (u64): CAP real + 1 garbage slot
#define NCH   6               // chunks per subset

typedef unsigned long long u64k;

// pd = -xx_n - (-2*dot) - xx_m with numpy rounding order.
// fma(dot,2,-xxn): 2*dot is exact => identical bits to round(2dot - xxn).
__device__ __forceinline__ float pd_np(float qx, float qy, float qz, float xxn,
                                       float cx, float cy, float cz, float xm) {
  float p0 = qx * cx;
  float p1 = qy * cy;
  float p2 = qz * cz;
  float dot = (p0 + p1) + p2;
  float t = __builtin_fmaf(dot, 2.0f, -xxn);
  return t - xm;
}

// values-only gated branchless sorted insert (ascending; keeps 20 largest)
__device__ __forceinline__ void insert20(float (&arr)[K_NN], float v) {
  float c = v;
#pragma unroll
  for (int u = K_NN - 1; u >= 0; --u) {
    float hi = fmaxf(arr[u], c);
    c = fminf(arr[u], c);
    arr[u] = hi;
  }
}

// packed-key sorted insert: key = (sortable_pd << 13) | (8191 - j)
// u64 descending == (pd desc, j asc) == jax.lax.top_k order (set semantics).
__device__ __forceinline__ void insK(u64k (&a)[K_NN], u64k k) {
  u64k c = k;
#pragma unroll
  for (int u = K_NN - 1; u >= 0; --u) {
    bool g = a[u] > c;
    u64k hi = g ? a[u] : c;
    u64k lo = g ? c : a[u];
    a[u] = hi;
    c = lo;
  }
}

__device__ __forceinline__ unsigned sortable32(float pd) {
  unsigned s = __float_as_uint(pd);
  return s ^ ((unsigned)((int)s >> 31) | 0x80000000u);
}

__device__ __forceinline__ u64k packKey(float pd, int j) {
  return ((u64k)sortable32(pd) << 13) | (unsigned)(8191 - j);
}

__device__ __forceinline__ float keyPd(u64k k) {
  unsigned sp = (unsigned)(k >> 13);
  unsigned s = (sp & 0x80000000u) ? (sp & 0x7FFFFFFFu) : ~sp;
  return __uint_as_float(s);
}

__global__ __launch_bounds__(256, 2)
void pack_kernel(const float* __restrict__ x, float4* __restrict__ P) {
  int idx = blockIdx.x * 256 + threadIdx.x;   // b*N + n
  if (idx >= B_SZ * N_PTS) return;
  int b = idx >> 13;
  int n = idx & (N_PTS - 1);
  const float* xb = x + (size_t)b * 3 * N_PTS;
  float x0 = xb[n];
  float x1 = xb[n + N_PTS];
  float x2 = xb[n + 2 * N_PTS];
  float xxv = (x0 * x0 + x1 * x1) + x2 * x2;  // numpy order, no contraction
  P[idx] = make_float4(x0, x1, x2, xxv);
}

__global__ __launch_bounds__(512, 4)
void knn_edgeconv_kernel(const float4* __restrict__ P,
                         const float* __restrict__ W,
                         const float* __restrict__ bias,
                         float* __restrict__ out) {
  __shared__ u64k  stk[2 * NSW * 64 * SPAD];   // double-buffered stacks (also warm scratch)
  __shared__ int   cnt2[2][NSW * 64];
  __shared__ float tau_l[QW];
  __shared__ int   list_l[QW][21];

  const int t  = threadIdx.x;
  const int ql = t & 63;
  const int s  = t >> 6;              // wave id: 0 = drain, 1..7 = scan
  const int wb = blockIdx.x;          // 0..511
  const int b  = wb >> 7;
  const int n0 = (wb & 127) << 6;
  const int q  = n0 + ql;

  // opaque zero: keeps candidate loads in VMEM/VGPR (counted vmcnt pipelining)
  int vz;
  asm volatile("v_mov_b32 %0, 0" : "=v"(vz));

  const float4* __restrict__ Pb = P + (size_t)b * N_PTS;

  const float4 qc = Pb[q];
  const float qx = qc.x, qy = qc.y, qz = qc.z, xxn = qc.w;

  const int sw   = __builtin_amdgcn_readfirstlane(s);
  const int j0   = (sw - 1) * SUBL;            // scan waves only
  const int LEN  = (sw == 7) ? (N_PTS - 6 * SUBL) : SUBL;   // 1172 for wave 7
  const int tid7 = ((sw - 1) << 6) | ql;       // 0..447 for scan waves
  const int CB[NCH + 1] = {0, 96, 192, 320, 512, 800, SUBL};

  // ---- Warm-up (scan waves): values-only top-20 of first WARM own candidates ----
  float arrv[K_NN];
#pragma unroll
  for (int i = 0; i < K_NN; ++i) arrv[i] = -__builtin_inff();
  if (s >= 1) {
#pragma unroll 4
    for (int jj = 0; jj < WARM; ++jj) {
      int j = j0 + jj;
      float4 cd = Pb[j + vz];
      float pd = pd_np(qx, qy, qz, xxn, cd.x, cd.y, cd.z, cd.w);
      if (pd > arrv[0]) insert20(arrv, pd);
    }
    float* WV = (float*)stk;
#pragma unroll
    for (int i = 0; i < K_NN; ++i) WV[tid7 * 21 + i] = arrv[i];
  }
  __syncthreads();

  // ---- Drain wave: merge 7 warm lists -> tau0 = exact 20th of 672-sample ----
  u64k karr[K_NN];
#pragma unroll
  for (int i = 0; i < K_NN; ++i) karr[i] = 0ULL;
  if (s == 0) {
    const float* WV = (const float*)stk;
    for (int p = 0; p < NSW; ++p) {
      const float* pv = WV + ((p << 6) + t) * 21;
      for (int i = 0; i < K_NN; ++i) {
        float v = pv[i];
        if (v > arrv[0]) insert20(arrv, v);
      }
    }
    tau_l[t] = arrv[0];
  }
  __syncthreads();

  // ---- Pipelined stages: scan chunk st (waves 1-7, BRANCHLESS) || drain st-1 (wave 0) ----
  // Branchless push: unconditional clamped-slot write; garbage lands at slot
  // cnt (one past last real push) and is never read. cnt>CAP => exact rescan.
#define PROC1(d, jv) {                                                   \
    float pdv = pd_np(qx, qy, qz, xxn, (d).x, (d).y, (d).z, (d).w);      \
    int slot = cnt < CAP ? cnt : CAP;                                    \
    my[slot] = ((u64k)__float_as_uint(pdv) << 32) | (unsigned)(jv);      \
    cnt += (pdv >= tau) ? 1 : 0;                                         \
  }
#define LOAD8(v, base)                                                   \
    v##0 = Pb[(base) + 0 + vz]; v##1 = Pb[(base) + 1 + vz];              \
    v##2 = Pb[(base) + 2 + vz]; v##3 = Pb[(base) + 3 + vz];              \
    v##4 = Pb[(base) + 4 + vz]; v##5 = Pb[(base) + 5 + vz];              \
    v##6 = Pb[(base) + 6 + vz]; v##7 = Pb[(base) + 7 + vz];
#define PROC8(v, base)                                                   \
    PROC1(v##0, (base) + 0) PROC1(v##1, (base) + 1)                      \
    PROC1(v##2, (base) + 2) PROC1(v##3, (base) + 3)                      \
    PROC1(v##4, (base) + 4) PROC1(v##5, (base) + 5)                      \
    PROC1(v##6, (base) + 6) PROC1(v##7, (base) + 7)

  for (int st = 0; st <= NCH; ++st) {
    if (s >= 1 && st < NCH) {
      const int c = st;
      const float tau = tau_l[ql];
      int cnt = 0;
      const int jb = j0 + CB[c];
      const int je = j0 + ((c == NCH - 1) ? LEN : CB[c + 1]);
      u64k* my = stk + (size_t)(c & 1) * (NSW * 64 * SPAD) + (size_t)tid7 * SPAD;
      int j = jb;
      float4 a0, a1, a2, a3, a4, a5, a6, a7;
      float4 b0, b1, b2, b3, b4, b5, b6, b7;
      if (j + 7 < je) {
        LOAD8(a, j)
        for (; j + 23 < je; j += 16) {        // 2-deep software pipeline
          LOAD8(b, j + 8)
          PROC8(a, j)
          LOAD8(a, j + 16)
          PROC8(b, j + 8)
        }
        if (j + 15 < je) {
          LOAD8(b, j + 8)
          PROC8(a, j)
          PROC8(b, j + 8)
          j += 16;
        } else {
          PROC8(a, j)
          j += 8;
        }
      }
      for (; j < je; ++j) {
        float4 d = Pb[j + vz];
        PROC1(d, j)
      }
      cnt2[c & 1][tid7] = cnt;
    }
    if (s == 0 && st >= 1) {
      const int c = st - 1;
      const float tauc = tau_l[t];
      const u64k* sb = stk + (size_t)(c & 1) * (NSW * 64 * SPAD);
      for (int p = 0; p < NSW; ++p) {
        const int pt = (p << 6) + t;
        int pc = cnt2[c & 1][pt];
        if (pc <= CAP) {
          const u64k* ps = sb + (size_t)pt * SPAD;
          for (int i = 0; i < pc; ++i) {
            u64k e = ps[i];
            float pdv = __uint_as_float((unsigned)(e >> 32));
            int jv = (int)(e & 0xFFFFFFFFu);
            u64k k = packKey(pdv, jv);
            if (k > karr[0]) insK(karr, k);
          }
        } else {                              // overflow: exact whole-chunk rescan
          int jb2 = p * SUBL + CB[c];
          int je2 = p * SUBL +
              ((c == NCH - 1) ? ((p == NSW - 1) ? (N_PTS - 6 * SUBL) : SUBL)
                              : CB[c + 1]);
          for (int j = jb2; j < je2; ++j) {
            float4 cd = Pb[j + vz];
            float pdv = pd_np(qx, qy, qz, xxn, cd.x, cd.y, cd.z, cd.w);
            if (pdv >= tauc) {
              u64k k = packKey(pdv, j);
              if (k > karr[0]) insK(karr, k);
            }
          }
        }
      }
      float t20 = keyPd(karr[0]);            // NaN while karr not full -> fmaxf keeps old
      tau_l[t] = fmaxf(tauc, t20);
    }
    __syncthreads();
  }
#undef PROC1
#undef LOAD8
#undef PROC8

  // ---- Publish final neighbor indices ----
  if (s == 0) {
#pragma unroll
    for (int i = 0; i < K_NN; ++i)
      list_l[t][i] = 8191 - (int)(karr[i] & 8191ULL);
  }
  __syncthreads();

  // ---- EdgeConv: max_j( W[:,0:3]·(x_m - x_n) ) + center term, leaky relu ----
  float acc[8];
#pragma unroll
  for (int oi = 0; oi < 8; ++oi) acc[oi] = -__builtin_inff();
  const int o0 = s * 8;
  const float* __restrict__ Wp = W + o0 * 6;

  for (int nb = 0; nb < K_NN; ++nb) {
    int m = list_l[ql][nb] & (N_PTS - 1);   // mask: memory-safety belt
    float4 cm = Pb[m];
    float dx = cm.x - qx;
    float dy = cm.y - qy;
    float dz = cm.z - qz;
#pragma unroll
    for (int oi = 0; oi < 8; ++oi) {
      float h = __builtin_fmaf(dz, Wp[oi * 6 + 2],
                __builtin_fmaf(dy, Wp[oi * 6 + 1], dx * Wp[oi * 6 + 0]));
      acc[oi] = fmaxf(acc[oi], h);
    }
  }

#pragma unroll
  for (int oi = 0; oi < 8; ++oi) {
    int o = o0 + oi;
    float base = __builtin_fmaf(qz, Wp[oi * 6 + 5],
                 __builtin_fmaf(qy, Wp[oi * 6 + 4], qx * Wp[oi * 6 + 3])) + bias[o];
    float v = acc[oi] + base;
    v = fmaxf(v, 0.2f * v);                 // leaky_relu (monotone, commutes with max)
    out[((size_t)(b * O_CH + o) << 13) + q] = v;
  }
}

extern "C" void kernel_launch(void* const* d_in, const int* in_sizes, int n_in,
                              void* d_out, int out_size, void* d_ws, size_t ws_size,
                              hipStream_t stream) {
  const float* x    = (const float*)d_in[0];
  const float* W    = (const float*)d_in[1];
  const float* bias = (const float*)d_in[2];
  float4* P  = (float4*)d_ws;               // B*N float4 = 512 KB
  float* out = (float*)d_out;

  pack_kernel<<<dim3((B_SZ * N_PTS + 255) / 256), dim3(256), 0, stream>>>(x, P);
  knn_edgeconv_kernel<<<dim3(B_SZ * (N_PTS / QW)), dim3(512), 0, stream>>>(P, W, bias, out);
}

// Round 7
// 401.984 us; speedup vs baseline: 2.4730x; 2.4730x over previous
//
#include <hip/hip_runtime.h>
#include <cstdint>

#pragma clang fp contract(off)

#define N_PTS 8192
#define B_SZ  4
#define K_NN  20
#define O_CH  64
#define QW    64              // queries per block (= lanes)
#define NWAVE 8
#define WARM  64              // warm candidates per wave (union = 512 = chunk 1)
#define CAPQ  56              // per-query per-chunk stack capacity
#define SPADQ 57              // stack row stride in u64
#define NCH   5

typedef unsigned long long u64k;

// pd = -xx_n - (-2*dot) - xx_m with numpy rounding order.
// fma(dot,2,-xxn): 2*dot is exact => identical bits to round(2dot - xxn).
__device__ __forceinline__ float pd_np(float qx, float qy, float qz, float xxn,
                                       float cx, float cy, float cz, float xm) {
  float p0 = qx * cx;
  float p1 = qy * cy;
  float p2 = qz * cz;
  float dot = (p0 + p1) + p2;
  float t = __builtin_fmaf(dot, 2.0f, -xxn);
  return t - xm;
}

// values-only gated branchless sorted insert (ascending; keeps 20 largest)
__device__ __forceinline__ void insert20(float (&arr)[K_NN], float v) {
  float c = v;
#pragma unroll
  for (int u = K_NN - 1; u >= 0; --u) {
    float hi = fmaxf(arr[u], c);
    c = fminf(arr[u], c);
    arr[u] = hi;
  }
}

// packed-key sorted insert: key = (sortable_pd << 13) | (8191 - j)
// u64 descending == (pd desc, j asc) == jax.lax.top_k order (set semantics).
__device__ __forceinline__ void insK(u64k (&a)[K_NN], u64k k) {
  u64k c = k;
#pragma unroll
  for (int u = K_NN - 1; u >= 0; --u) {
    bool g = a[u] > c;
    u64k hi = g ? a[u] : c;
    u64k lo = g ? c : a[u];
    a[u] = hi;
    c = lo;
  }
}

__device__ __forceinline__ unsigned sortable32(float pd) {
  unsigned s = __float_as_uint(pd);
  return s ^ ((unsigned)((int)s >> 31) | 0x80000000u);
}

__device__ __forceinline__ u64k packKey(float pd, int j) {
  return ((u64k)sortable32(pd) << 13) | (unsigned)(8191 - j);
}

__device__ __forceinline__ float keyPd(u64k k) {
  unsigned sp = (unsigned)(k >> 13);
  unsigned s = (sp & 0x80000000u) ? (sp & 0x7FFFFFFFu) : ~sp;
  return __uint_as_float(s);
}

__global__ __launch_bounds__(256, 2)
void pack_kernel(const float* __restrict__ x, float4* __restrict__ P) {
  int idx = blockIdx.x * 256 + threadIdx.x;   // b*N + n
  if (idx >= B_SZ * N_PTS) return;
  int b = idx >> 13;
  int n = idx & (N_PTS - 1);
  const float* xb = x + (size_t)b * 3 * N_PTS;
  float x0 = xb[n];
  float x1 = xb[n + N_PTS];
  float x2 = xb[n + 2 * N_PTS];
  float xxv = (x0 * x0 + x1 * x1) + x2 * x2;  // numpy order, no contraction
  P[idx] = make_float4(x0, x1, x2, xxv);
}

__global__ __launch_bounds__(512, 4)
void knn_edgeconv_kernel(const float4* __restrict__ P,
                         const float* __restrict__ W,
                         const float* __restrict__ bias,
                         float* __restrict__ out) {
  __shared__ u64k  smem[5376];        // 43008 B: warm scratch (512x21 f32) aliased
                                      // with per-query stacks (64 x 57 u64)
  __shared__ float tau_l[QW];
  __shared__ int   cnt_l[QW];
  __shared__ int   list_l[QW][21];

  const int t  = threadIdx.x;
  const int ql = t & 63;
  const int s  = t >> 6;              // wave id 0..7
  const int wb = blockIdx.x;          // 0..511
  const int b  = wb >> 7;
  const int n0 = (wb & 127) << 6;
  const int q  = n0 + ql;

  const float4* __restrict__ Pb = P + (size_t)b * N_PTS;
  const float4* __restrict__ Pq = Pb + n0;    // query tile (1 KB, L1-resident)

  const float4 qc = Pb[q];
  const float qx = qc.x, qy = qc.y, qz = qc.z, xxn = qc.w;

  const int sw  = __builtin_amdgcn_readfirstlane(s);
  const int myq = (sw << 3) + ql;     // drain-role query (lanes ql<8 of each wave)

  // ---- Warm: wave w scans candidates [w*64,(w+1)*64) for its lane-query ----
  float arrv[K_NN];
#pragma unroll
  for (int i = 0; i < K_NN; ++i) arrv[i] = -__builtin_inff();
  {
    const int jb = sw * WARM;
    for (int jj = 0; jj < WARM; ++jj) {
      float4 cd = Pb[jb + jj];
      float pdv = pd_np(qx, qy, qz, xxn, cd.x, cd.y, cd.z, cd.w);
      if (pdv > arrv[0]) insert20(arrv, pdv);
    }
    float* WV = (float*)smem;
#pragma unroll
    for (int i = 0; i < K_NN; ++i) WV[t * 21 + i] = arrv[i];
  }
  __syncthreads();

  // ---- Merge warm lists -> tau0 = exact 20th of [0,512) (8 waves x 8 lanes) ----
  u64k karr[K_NN];
#pragma unroll
  for (int i = 0; i < K_NN; ++i) karr[i] = 0ULL;
  if (ql < 8) {
    const float* WV = (const float*)smem;
    float m[K_NN];
#pragma unroll
    for (int i = 0; i < K_NN; ++i) m[i] = -__builtin_inff();
    for (int p = 0; p < NWAVE; ++p) {
      const float* pv = WV + ((p << 6) + myq) * 21;
      for (int i = 0; i < K_NN; ++i) {
        float v = pv[i];
        if (v > m[0]) insert20(m, v);
      }
    }
    tau_l[myq] = m[0];
    cnt_l[myq] = 0;
  }
  __syncthreads();

  // ---- Transposed filtered scan over geometric chunks (lambda = 20/chunk) ----
  // Lane holds candidate; inner loop over 64 queries (uniform s_load + readlane).
  const int CB[NCH + 1] = {0, 512, 1024, 2048, 4096, 8192};
  u64k* stk = smem;

  for (int c = 0; c < NCH; ++c) {
    {
      const int csz  = CB[c + 1] - CB[c];
      const int nbat = csz >> 9;                   // batches of 64 per wave
      const int jb   = CB[c] + sw * (csz >> 3);
      const int tau_own = __float_as_int(tau_l[ql]);  // lane l holds tau[query l]
      for (int bt = 0; bt < nbat; ++bt) {
        const int j = jb + (bt << 6) + ql;         // per-lane candidate (coalesced)
        const float4 cd = Pb[j];
        const float cx = cd.x, cy = cd.y, cz = cd.z, cw = cd.w;
#pragma unroll 4
        for (int qi = 0; qi < QW; ++qi) {
          const float4 qv = Pq[qi];                // uniform -> scalar load
          const float stau = __int_as_float(__builtin_amdgcn_readlane(tau_own, qi));
          float pdv = pd_np(qv.x, qv.y, qv.z, qv.w, cx, cy, cz, cw);
          if (pdv >= stau) {                       // >= : keep boundary ties
            int slot = atomicAdd(&cnt_l[qi], 1);
            if (slot < CAPQ)
              stk[qi * SPADQ + slot] =
                  ((u64k)__float_as_uint(pdv) << 32) | (unsigned)j;
          }
        }
      }
    }
    __syncthreads();

    // ---- Drain: wave w lanes 0..7 handle queries w*8..w*8+7 (lane-parallel) ----
    if (ql < 8) {
      const float tauc = tau_l[myq];
      const int pc = cnt_l[myq];
      if (pc <= CAPQ) {
        for (int i = 0; i < pc; ++i) {
          u64k e = stk[myq * SPADQ + i];
          float pdv = __uint_as_float((unsigned)(e >> 32));
          int jv = (int)(e & 0xFFFFFFFFu);
          u64k k = packKey(pdv, jv);
          if (k > karr[0]) insK(karr, k);
        }
      } else {                                     // rare: exact whole-chunk rescan
        float4 mq = Pq[myq];
        for (int j = CB[c]; j < CB[c + 1]; ++j) {
          float4 cd = Pb[j];
          float pdv = pd_np(mq.x, mq.y, mq.z, mq.w, cd.x, cd.y, cd.z, cd.w);
          if (pdv >= tauc) {
            u64k k = packKey(pdv, j);
            if (k > karr[0]) insK(karr, k);
          }
        }
      }
      cnt_l[myq] = 0;
      float t20 = keyPd(karr[0]);                  // NaN while not full -> fmaxf keeps old
      tau_l[myq] = fmaxf(tauc, t20);
    }
    __syncthreads();
  }

  // ---- Publish final neighbor indices ----
  if (ql < 8) {
#pragma unroll
    for (int i = 0; i < K_NN; ++i)
      list_l[myq][i] = 8191 - (int)(karr[i] & 8191ULL);
  }
  __syncthreads();

  // ---- EdgeConv: max_j( W[:,0:3]·(x_m - x_n) ) + center term, leaky relu ----
  float acc[8];
#pragma unroll
  for (int oi = 0; oi < 8; ++oi) acc[oi] = -__builtin_inff();
  const int o0 = s * 8;
  const float* __restrict__ Wp = W + o0 * 6;

  for (int nb = 0; nb < K_NN; ++nb) {
    int m = list_l[ql][nb] & (N_PTS - 1);   // mask: memory-safety belt
    float4 cm = Pb[m];
    float dx = cm.x - qx;
    float dy = cm.y - qy;
    float dz = cm.z - qz;
#pragma unroll
    for (int oi = 0; oi < 8; ++oi) {
      float h = __builtin_fmaf(dz, Wp[oi * 6 + 2],
                __builtin_fmaf(dy, Wp[oi * 6 + 1], dx * Wp[oi * 6 + 0]));
      acc[oi] = fmaxf(acc[oi], h);
    }
  }

#pragma unroll
  for (int oi = 0; oi < 8; ++oi) {
    int o = o0 + oi;
    float base = __builtin_fmaf(qz, Wp[oi * 6 + 5],
                 __builtin_fmaf(qy, Wp[oi * 6 + 4], qx * Wp[oi * 6 + 3])) + bias[o];
    float v = acc[oi] + base;
    v = fmaxf(v, 0.2f * v);                 // leaky_relu (monotone, commutes with max)
    out[((size_t)(b * O_CH + o) << 13) + q] = v;
  }
}

extern "C" void kernel_launch(void* const* d_in, const int* in_sizes, int n_in,
                              void* d_out, int out_size, void* d_ws, size_t ws_size,
                              hipStream_t stream) {
  const float* x    = (const float*)d_in[0];
  const float* W    = (const float*)d_in[1];
  const float* bias = (const float*)d_in[2];
  float4* P  = (float4*)d_ws;               // B*N float4 = 512 KB
  float* out = (float*)d_out;

  pack_kernel<<<dim3((B_SZ * N_PTS + 255) / 256), dim3(256), 0, stream>>>(x, P);
  knn_edgeconv_kernel<<<dim3(B_SZ * (N_PTS / QW)), dim3(512), 0, stream>>>(P, W, bias, out);
}